// Round 2
// baseline (1107.678 us; speedup 1.0000x reference)
//
#include <hip/hip_runtime.h>
#include <math.h>

// L2ClusterCentroid: N=1e6 rows, D=128, C=100.
// assign = argmax(logits, -1); centroids = segment_mean(embedding, assign);
// out[c] = counts[c]>0 ? ||centers[c] - centroids[c]||_2 : 0
//
// Phase 1: per-block LDS accumulation of segment sums/counts over a contiguous
//          row chunk; write per-block partials to d_ws (deterministic, no
//          global atomics, no ws pre-zeroing needed).
// Phase 2: fixed-order reduction over partials + distance epilogue.

#define NROWS 1000000
#define DIM   128
#define NCLS  100
#define SLICE (NCLS * DIM + NCLS)   // 12900 floats per block partial
#define P1_THREADS 512

__global__ __launch_bounds__(P1_THREADS)
void l2cc_phase1(const float* __restrict__ emb,
                 const float* __restrict__ logits,
                 float* __restrict__ partial,
                 int rows_per_block)
{
    __shared__ float s_acc[SLICE];  // [c*DIM + d] sums, counts at NCLS*DIM + c
    const int tid = threadIdx.x;
    for (int i = tid; i < SLICE; i += P1_THREADS) s_acc[i] = 0.0f;
    __syncthreads();

    const int b    = blockIdx.x;
    const int wave = tid >> 6;   // 0..7
    const int lane = tid & 63;

    const int start = b * rows_per_block;
    const int end   = min(start + rows_per_block, NROWS);

    for (int row = start + wave; row < end; row += (P1_THREADS / 64)) {
        // ---- wave-cooperative argmax over logits[row][0..99] ----
        const float* lrow = logits + (long long)row * NCLS;
        float v = lrow[lane];          // lane < 64 < 100: always valid
        int   k = lane;
        if (lane + 64 < NCLS) {
            float v1 = lrow[lane + 64];
            if (v1 > v) { v = v1; k = lane + 64; }   // tie -> keep smaller idx
        }
        #pragma unroll
        for (int off = 32; off > 0; off >>= 1) {
            float ov = __shfl_xor(v, off, 64);
            int   ok = __shfl_xor(k, off, 64);
            if (ov > v || (ov == v && ok < k)) { v = ov; k = ok; }
        }
        // k is wave-uniform now.

        // ---- accumulate embedding row into LDS segment sums ----
        const float2 e = *reinterpret_cast<const float2*>(
            emb + (long long)row * DIM + lane * 2);
        float* dst = s_acc + k * DIM + lane * 2;
        atomicAdd(dst,     e.x);
        atomicAdd(dst + 1, e.y);
        if (lane == 0) atomicAdd(s_acc + NCLS * DIM + k, 1.0f);
    }
    __syncthreads();

    float* p = partial + (long long)b * SLICE;
    for (int i = tid; i < SLICE; i += P1_THREADS) p[i] = s_acc[i];
}

__global__ __launch_bounds__(128)
void l2cc_phase2(const float* __restrict__ partial,
                 const float* __restrict__ centers,
                 float* __restrict__ out,
                 int nblocks)
{
    const int c = blockIdx.x;    // 0..99
    const int t = threadIdx.x;   // 0..127

    // deterministic fixed-order sum over block partials
    float s = 0.0f;
    for (int b = 0; b < nblocks; ++b)
        s += partial[(long long)b * SLICE + c * DIM + t];

    float cnt = 0.0f;
    for (int b = 0; b < nblocks; ++b)
        cnt += partial[(long long)b * SLICE + NCLS * DIM + c];

    const float centroid = s / fmaxf(cnt, 1.0f);
    const float d  = centers[c * DIM + t] - centroid;
    float sq = d * d;

    // reduce 128 threads (2 waves)
    #pragma unroll
    for (int off = 32; off > 0; off >>= 1) sq += __shfl_xor(sq, off, 64);

    __shared__ float red[2];
    if ((t & 63) == 0) red[t >> 6] = sq;
    __syncthreads();
    if (t == 0) {
        const float total = red[0] + red[1];
        const float dist  = (total > 0.0f) ? sqrtf(total) : 0.0f;
        out[c] = (cnt > 0.0f) ? dist : 0.0f;
    }
}

extern "C" void kernel_launch(void* const* d_in, const int* in_sizes, int n_in,
                              void* d_out, int out_size, void* d_ws, size_t ws_size,
                              hipStream_t stream)
{
    const float* emb     = (const float*)d_in[0];  // [N, 128]
    const float* centers = (const float*)d_in[1];  // [100, 128]
    const float* logits  = (const float*)d_in[2];  // [N, 100]
    float* out = (float*)d_out;                    // [100]
    float* partial = (float*)d_ws;

    // choose block count to fit workspace (need B * SLICE * 4 bytes)
    int B = (int)(ws_size / (SLICE * sizeof(float)));
    if (B > 512) B = 512;
    if (B < 1)   B = 1;   // assume ws_size >= one slice (51.6 KB)

    const int rows_per_block = (NROWS + B - 1) / B;

    l2cc_phase1<<<B, P1_THREADS, 0, stream>>>(emb, logits, partial, rows_per_block);
    l2cc_phase2<<<NCLS, 128, 0, stream>>>(partial, centers, out, B);
}

// Round 3
// 952.496 us; speedup vs baseline: 1.1629x; 1.1629x over previous
//
#include <hip/hip_runtime.h>
#include <math.h>

// L2ClusterCentroid: N=1e6 rows, D=128, C=100.
// assign = argmax(logits, -1); centroids = segment_mean(embedding, assign);
// out[c] = counts[c]>0 ? ||centers[c] - centroids[c]||_2 : 0
//
// Round-3 structure: fused single pass, but 8 rows per wave-iteration so
// loads/shuffles/atomics from independent rows pipeline (round-2 version was
// latency-bound at 8800 cyc/row: 1 row in flight per wave).
// Argmax = 6-step shfl-max on value only + 2 ballots for first-index argmax.
// LDS accumulator stores dims permuted (e.x -> slot lane, e.y -> slot 64+lane)
// so atomic bank aliasing is 2-way (free) instead of 4-way.

#define NROWS 1000000
#define DIM   128
#define NCLS  100
#define SLICE (NCLS * DIM + NCLS)   // 12900 floats per block partial
#define P1_THREADS 512
#define GRP 8                        // rows per wave-iteration

__global__ __launch_bounds__(P1_THREADS)
void l2cc_phase1(const float* __restrict__ emb,
                 const float* __restrict__ logits,
                 float* __restrict__ partial,
                 int rows_per_block)
{
    __shared__ float s_acc[SLICE];  // sums permuted: [c*128 + p], counts at 12800+c
    const int tid = threadIdx.x;
    for (int i = tid; i < SLICE; i += P1_THREADS) s_acc[i] = 0.0f;
    __syncthreads();

    const int b    = blockIdx.x;
    const int wave = tid >> 6;   // 0..7
    const int lane = tid & 63;

    const int start = b * rows_per_block;
    const int end   = min(start + rows_per_block, NROWS);

    for (int r0 = start + wave * GRP; r0 < end; r0 += (P1_THREADS / 64) * GRP) {
        const int ng = min(GRP, end - r0);
        if (ng == GRP) {
            // ---- issue all loads for 8 rows up front (independent, pipelined) ----
            float  va[GRP], vb[GRP];
            float2 e[GRP];
            #pragma unroll
            for (int j = 0; j < GRP; ++j) {
                const float* lrow = logits + (size_t)(r0 + j) * NCLS;
                va[j] = lrow[lane];
                vb[j] = (lane < NCLS - 64) ? lrow[lane + 64] : -INFINITY;
                e[j]  = *reinterpret_cast<const float2*>(
                            emb + (size_t)(r0 + j) * DIM + lane * 2);
            }
            // ---- argmax per row: shfl-max on value, ballot for first index ----
            int kk[GRP];
            #pragma unroll
            for (int j = 0; j < GRP; ++j) {
                float v = fmaxf(va[j], vb[j]);
                #pragma unroll
                for (int off = 32; off > 0; off >>= 1)
                    v = fmaxf(v, __shfl_xor(v, off, 64));
                unsigned long long m1 = __ballot(va[j] == v);  // cols 0..63
                unsigned long long m2 = __ballot(vb[j] == v);  // cols 64..99
                kk[j] = m1 ? (__ffsll((long long)m1) - 1)
                           : (__ffsll((long long)m2) + 63);
            }
            // ---- accumulate (permuted layout: 2-way bank aliasing = free) ----
            #pragma unroll
            for (int j = 0; j < GRP; ++j) {
                float* base = s_acc + kk[j] * DIM;
                atomicAdd(base + lane,      e[j].x);   // dim 2*lane
                atomicAdd(base + 64 + lane, e[j].y);   // dim 2*lane+1
            }
            if (lane == 0) {
                #pragma unroll
                for (int j = 0; j < GRP; ++j)
                    atomicAdd(s_acc + NCLS * DIM + kk[j], 1.0f);
            }
        } else {
            for (int j = 0; j < ng; ++j) {
                const float* lrow = logits + (size_t)(r0 + j) * NCLS;
                float va0 = lrow[lane];
                float vb0 = (lane < NCLS - 64) ? lrow[lane + 64] : -INFINITY;
                float2 e0 = *reinterpret_cast<const float2*>(
                                emb + (size_t)(r0 + j) * DIM + lane * 2);
                float v = fmaxf(va0, vb0);
                #pragma unroll
                for (int off = 32; off > 0; off >>= 1)
                    v = fmaxf(v, __shfl_xor(v, off, 64));
                unsigned long long m1 = __ballot(va0 == v);
                unsigned long long m2 = __ballot(vb0 == v);
                int k = m1 ? (__ffsll((long long)m1) - 1)
                           : (__ffsll((long long)m2) + 63);
                float* base = s_acc + k * DIM;
                atomicAdd(base + lane,      e0.x);
                atomicAdd(base + 64 + lane, e0.y);
                if (lane == 0) atomicAdd(s_acc + NCLS * DIM + k, 1.0f);
            }
        }
    }
    __syncthreads();

    float* p = partial + (size_t)b * SLICE;
    for (int i = tid; i < SLICE; i += P1_THREADS) p[i] = s_acc[i];
}

__global__ __launch_bounds__(128)
void l2cc_phase2(const float* __restrict__ partial,
                 const float* __restrict__ centers,
                 float* __restrict__ out,
                 int nblocks)
{
    const int c = blockIdx.x;    // 0..99
    const int t = threadIdx.x;   // 0..127 = permuted slot index

    // slot t holds dim d: t<64 -> d=2t (e.x of lane t); t>=64 -> d=2t-127
    const int d = (t < 64) ? (2 * t) : (2 * t - 127);

    float s = 0.0f;
    for (int b = 0; b < nblocks; ++b)
        s += partial[(size_t)b * SLICE + c * DIM + t];

    float cnt = 0.0f;
    for (int b = 0; b < nblocks; ++b)
        cnt += partial[(size_t)b * SLICE + NCLS * DIM + c];

    const float centroid = s / fmaxf(cnt, 1.0f);
    const float dd = centers[c * DIM + d] - centroid;
    float sq = dd * dd;

    #pragma unroll
    for (int off = 32; off > 0; off >>= 1) sq += __shfl_xor(sq, off, 64);

    __shared__ float red[2];
    if ((t & 63) == 0) red[t >> 6] = sq;
    __syncthreads();
    if (t == 0) {
        const float total = red[0] + red[1];
        const float dist  = (total > 0.0f) ? sqrtf(total) : 0.0f;
        out[c] = (cnt > 0.0f) ? dist : 0.0f;
    }
}

extern "C" void kernel_launch(void* const* d_in, const int* in_sizes, int n_in,
                              void* d_out, int out_size, void* d_ws, size_t ws_size,
                              hipStream_t stream)
{
    const float* emb     = (const float*)d_in[0];  // [N, 128]
    const float* centers = (const float*)d_in[1];  // [100, 128]
    const float* logits  = (const float*)d_in[2];  // [N, 100]
    float* out = (float*)d_out;                    // [100]
    float* partial = (float*)d_ws;

    int B = (int)(ws_size / (SLICE * sizeof(float)));
    if (B > 512) B = 512;
    if (B < 1)   B = 1;

    const int rows_per_block = (NROWS + B - 1) / B;

    l2cc_phase1<<<B, P1_THREADS, 0, stream>>>(emb, logits, partial, rows_per_block);
    l2cc_phase2<<<NCLS, 128, 0, stream>>>(partial, centers, out, B);
}

// Round 4
// 754.154 us; speedup vs baseline: 1.4688x; 1.2630x over previous
//
#include <hip/hip_runtime.h>
#include <math.h>

// L2ClusterCentroid: N=1e6 rows, D=128, C=100.
// assign = argmax(logits, -1); centroids = segment_mean(embedding, assign);
// out[c] = counts[c]>0 ? ||centers[c] - centroids[c]||_2 : 0
//
// Round-4: round-3 was latency-bound with ~1 outstanding load/wave
// (VGPR=40 forced the compiler to serialize the 8-row batch). Now:
//  - explicit A/B ping-pong software pipeline (static buffer names),
//  - __launch_bounds__(512,4) -> 128-VGPR budget so 2 batches stay in regs,
//  - branchless 2nd logits read (cols 36..99; overlap harmless for argmax),
//  - phase2 block-sum split 4-way (was 219us of serial-latency loads).

#define NROWS 1000000
#define DIM   128
#define NCLS  100
#define SLICE (NCLS * DIM + NCLS)   // 12900 floats per block partial
#define P1_THREADS 512
#define NWAVE (P1_THREADS / 64)
#define GRP 8                        // rows per batch
#define STRIDE (NWAVE * GRP)         // rows per block-iteration

__device__ __forceinline__ void load_batch(const float* __restrict__ emb,
                                           const float* __restrict__ logits,
                                           int r0, int lane,
                                           float va[GRP], float vb[GRP], float2 e[GRP])
{
    #pragma unroll
    for (int j = 0; j < GRP; ++j) {
        const float* lrow = logits + (size_t)(r0 + j) * NCLS;
        va[j] = lrow[lane];          // cols 0..63
        vb[j] = lrow[36 + lane];     // cols 36..99 (overlap 36..63 harmless)
        e[j]  = *reinterpret_cast<const float2*>(
                    emb + (size_t)(r0 + j) * DIM + lane * 2);
    }
}

__device__ __forceinline__ void process_batch(float* __restrict__ s_acc, int lane,
                                              const float va[GRP], const float vb[GRP],
                                              const float2 e[GRP])
{
    int kk[GRP];
    #pragma unroll
    for (int j = 0; j < GRP; ++j) {
        float v = fmaxf(va[j], vb[j]);
        #pragma unroll
        for (int off = 32; off > 0; off >>= 1)
            v = fmaxf(v, __shfl_xor(v, off, 64));
        unsigned long long m1 = __ballot(va[j] == v);   // col = lane
        unsigned long long m2 = __ballot(vb[j] == v);   // col = lane + 36
        int i1 = m1 ? (__ffsll((long long)m1) - 1) : 1000;
        int i2 = m2 ? (__ffsll((long long)m2) + 35) : 1000;
        kk[j] = min(i1, i2);        // first-index tie-break
    }
    #pragma unroll
    for (int j = 0; j < GRP; ++j) {
        float* base = s_acc + kk[j] * DIM;   // permuted: e.x->slot lane, e.y->64+lane
        atomicAdd(base + lane,      e[j].x);
        atomicAdd(base + 64 + lane, e[j].y);
    }
    // counts: lane j adds row j's count (static-index select chain)
    int myk = kk[0];
    #pragma unroll
    for (int j = 1; j < GRP; ++j) myk = (lane == j) ? kk[j] : myk;
    if (lane < GRP) atomicAdd(s_acc + NCLS * DIM + myk, 1.0f);
}

__device__ __forceinline__ void process_row(float* __restrict__ s_acc, int lane,
                                            const float* __restrict__ emb,
                                            const float* __restrict__ logits, int row)
{
    const float* lrow = logits + (size_t)row * NCLS;
    float va = lrow[lane];
    float vb = lrow[36 + lane];
    float2 e = *reinterpret_cast<const float2*>(emb + (size_t)row * DIM + lane * 2);
    float v = fmaxf(va, vb);
    #pragma unroll
    for (int off = 32; off > 0; off >>= 1)
        v = fmaxf(v, __shfl_xor(v, off, 64));
    unsigned long long m1 = __ballot(va == v);
    unsigned long long m2 = __ballot(vb == v);
    int i1 = m1 ? (__ffsll((long long)m1) - 1) : 1000;
    int i2 = m2 ? (__ffsll((long long)m2) + 35) : 1000;
    int k = min(i1, i2);
    float* base = s_acc + k * DIM;
    atomicAdd(base + lane,      e.x);
    atomicAdd(base + 64 + lane, e.y);
    if (lane == 0) atomicAdd(s_acc + NCLS * DIM + k, 1.0f);
}

__global__ __launch_bounds__(P1_THREADS, 4)
void l2cc_phase1(const float* __restrict__ emb,
                 const float* __restrict__ logits,
                 float* __restrict__ partial,
                 int rows_per_block)
{
    __shared__ float s_acc[SLICE];
    const int tid = threadIdx.x;
    for (int i = tid; i < SLICE; i += P1_THREADS) s_acc[i] = 0.0f;
    __syncthreads();

    const int b    = blockIdx.x;
    const int wave = tid >> 6;
    const int lane = tid & 63;

    const int start = b * rows_per_block;
    const int end   = min(start + rows_per_block, NROWS);
    const int r0    = start + wave * GRP;

    // number of full GRP batches for this wave
    int nb = 0;
    if (r0 + GRP <= end) nb = (end - r0 - GRP) / STRIDE + 1;

    float vaA[GRP], vbA[GRP]; float2 eA[GRP];
    float vaB[GRP], vbB[GRP]; float2 eB[GRP];

    if (nb > 0) {
        load_batch(emb, logits, r0, lane, vaA, vbA, eA);
        int i = 0;
        while (i + 2 <= nb) {
            load_batch(emb, logits, r0 + (i + 1) * STRIDE, lane, vaB, vbB, eB);
            process_batch(s_acc, lane, vaA, vbA, eA);
            if (i + 2 < nb)
                load_batch(emb, logits, r0 + (i + 2) * STRIDE, lane, vaA, vbA, eA);
            process_batch(s_acc, lane, vaB, vbB, eB);
            i += 2;
        }
        if (i < nb) process_batch(s_acc, lane, vaA, vbA, eA);  // odd remainder
    }

    // at most one partial batch remains
    const int r_tail = r0 + nb * STRIDE;
    for (int row = r_tail; row < min(r_tail + GRP, end); ++row)
        process_row(s_acc, lane, emb, logits, row);

    __syncthreads();
    float* p = partial + (size_t)b * SLICE;
    for (int i = tid; i < SLICE; i += P1_THREADS) p[i] = s_acc[i];
}

__global__ __launch_bounds__(512)
void l2cc_phase2(const float* __restrict__ partial,
                 const float* __restrict__ centers,
                 float* __restrict__ out,
                 int nblocks)
{
    const int c = blockIdx.x;          // 0..99
    const int t = threadIdx.x & 127;   // permuted slot
    const int g = threadIdx.x >> 7;    // 0..3 sub-reducer

    __shared__ float s_sum[4][128];
    __shared__ float s_cnt[4];
    __shared__ float s_red[8];

    float s = 0.0f;
    #pragma unroll 4
    for (int b = g; b < nblocks; b += 4)
        s += partial[(size_t)b * SLICE + c * DIM + t];
    s_sum[g][t] = s;

    float cn = 0.0f;
    for (int b = g; b < nblocks; b += 4)
        cn += partial[(size_t)b * SLICE + NCLS * DIM + c];
    if (t == 0) s_cnt[g] = cn;
    __syncthreads();

    float sq = 0.0f;
    float cnt = ((s_cnt[0] + s_cnt[1]) + s_cnt[2]) + s_cnt[3];
    if (threadIdx.x < 128) {
        const float tot = ((s_sum[0][t] + s_sum[1][t]) + s_sum[2][t]) + s_sum[3][t];
        // slot t<64 -> dim 2t ; t>=64 -> dim 2t-127
        const int d = (t < 64) ? (2 * t) : (2 * t - 127);
        const float centroid = tot / fmaxf(cnt, 1.0f);
        const float dd = centers[c * DIM + d] - centroid;
        sq = dd * dd;
    }
    #pragma unroll
    for (int off = 32; off > 0; off >>= 1) sq += __shfl_xor(sq, off, 64);
    if ((threadIdx.x & 63) == 0) s_red[threadIdx.x >> 6] = sq;
    __syncthreads();
    if (threadIdx.x == 0) {
        const float total = s_red[0] + s_red[1];  // waves 2..7 contributed 0
        const float dist  = (total > 0.0f) ? sqrtf(total) : 0.0f;
        out[c] = (cnt > 0.0f) ? dist : 0.0f;
    }
}

extern "C" void kernel_launch(void* const* d_in, const int* in_sizes, int n_in,
                              void* d_out, int out_size, void* d_ws, size_t ws_size,
                              hipStream_t stream)
{
    const float* emb     = (const float*)d_in[0];  // [N, 128]
    const float* centers = (const float*)d_in[1];  // [100, 128]
    const float* logits  = (const float*)d_in[2];  // [N, 100]
    float* out = (float*)d_out;                    // [100]
    float* partial = (float*)d_ws;

    int B = (int)(ws_size / (SLICE * sizeof(float)));
    if (B > 512) B = 512;
    if (B < 1)   B = 1;

    const int rows_per_block = (NROWS + B - 1) / B;

    l2cc_phase1<<<B, P1_THREADS, 0, stream>>>(emb, logits, partial, rows_per_block);
    l2cc_phase2<<<NCLS, 512, 0, stream>>>(partial, centers, out, B);
}